// Round 5
// baseline (654.827 us; speedup 1.0000x reference)
//
#include <hip/hip_runtime.h>

// ============================================================================
// 2-layer transformer encoder (B=1024, T=128, D=128, H=8, HD=16, FF=512)
// R5: 4-kernel pipeline. The monolith is structurally stuck: 154 KiB LDS ->
// 1 block/CU; 512-thr -> 2 waves/SIMD latency-bound (477us); 1024-thr ->
// 128-reg/wave budget -> unavoidable spills (R2-R4). Split stages into
// small-LDS high-occupancy kernels, bf16 intermediates via HBM (3% utilized).
//   prep: weights+x -> bf16 (ws)
//   K1: QKV GEMM -> q (ws, per-head layout), k/v (d_out used as scratch!)
//   K2: attention per (b,h), 8192 blocks; o overwrites q in ws
//   K3: out-proj + bias + residual + LN1 -> xbuf in-place
//   K4: FF1+relu+FF2 + residual + LN2 -> xbuf (l=0) / fp32 d_out (l=1)
// ws layout (shorts): weights 393216 | q/o 16777216 | xbuf 16777216 (~68MB)
// d_out (67.1MB) holds k|v scratch until K4 of layer 1 overwrites it.
// ============================================================================

typedef __attribute__((ext_vector_type(8))) __bf16 bf16x8;
typedef __attribute__((ext_vector_type(4))) float fx4;

#define MFMA16(a, b, c) __builtin_amdgcn_mfma_f32_16x16x32_bf16((a), (b), (c), 0, 0, 0)

static __device__ __forceinline__ unsigned short f2bf(float f) {
    __bf16 b = (__bf16)f;
    return __builtin_bit_cast(unsigned short, b);
}
static __device__ __forceinline__ float bf2f(unsigned short u) {
    return (float)__builtin_bit_cast(__bf16, u);
}

// --------------------------------------------------------------------------
// prep: weights fp32->bf16 (first 98304 float4s) then x fp32->bf16 (4194304).
// grid 16768 x 256 covers 4292608 float4s exactly.
// --------------------------------------------------------------------------
extern "C" __global__ void __launch_bounds__(256)
prep(const float* __restrict__ w_in, const float* __restrict__ w_out,
     const float* __restrict__ w_ff1, const float* __restrict__ w_ff2,
     const float* __restrict__ x,
     unsigned short* __restrict__ wsw, unsigned short* __restrict__ xbuf) {
    int i4 = blockIdx.x * 256 + threadIdx.x;
    if (i4 < 98304) {
        float4 v;
        if (i4 < 24576)      v = *(const float4*)(w_in  + i4 * 4);
        else if (i4 < 32768) v = *(const float4*)(w_out + (i4 - 24576) * 4);
        else if (i4 < 65536) v = *(const float4*)(w_ff1 + (i4 - 32768) * 4);
        else                 v = *(const float4*)(w_ff2 + (i4 - 65536) * 4);
        ushort4 o;
        o.x = f2bf(v.x); o.y = f2bf(v.y); o.z = f2bf(v.z); o.w = f2bf(v.w);
        *(ushort4*)(wsw + i4 * 4) = o;
    } else {
        size_t j = (size_t)(i4 - 98304) * 4;
        float4 v = *(const float4*)(x + j);
        ushort4 o;
        o.x = f2bf(v.x); o.y = f2bf(v.y); o.z = f2bf(v.z); o.w = f2bf(v.w);
        *(ushort4*)(xbuf + j) = o;
    }
}

// --------------------------------------------------------------------------
// K1: QKV projection. Block = one b, 512 thr (8 waves). Wave w = head w.
// q,k -> [b*8+h][t][16]; v -> [b*8+h][d][128] (transposed).
// --------------------------------------------------------------------------
extern "C" __global__ void __launch_bounds__(512, 4)
k_qkv(const unsigned short* __restrict__ xbuf,
      const unsigned short* __restrict__ w_inp,
      const float* __restrict__ inp_b,
      unsigned short* __restrict__ qbuf,
      unsigned short* __restrict__ kbuf,
      unsigned short* __restrict__ vbuf, int l) {
    __shared__ __align__(16) unsigned short xs[128 * 136];
    const int tid = threadIdx.x, w = tid >> 6, lid = tid & 63;
    const int l15 = lid & 15, kg = lid >> 4, b = blockIdx.x;

    const unsigned short* xb = xbuf + (size_t)b * 16384;
    #pragma unroll
    for (int i = 0; i < 4; ++i) {
        int e = i * 4096 + tid * 8;
        int row = e >> 7, col = e & 127;
        *(float4*)(xs + row * 136 + col) = *(const float4*)(xb + e);
    }
    __syncthreads();

    const size_t obase = ((size_t)b * 8 + w) * 2048;
    #pragma unroll 1
    for (int i = 0; i < 3; ++i) {               // 0=q 1=k 2=v
        const int nrow = l * 384 + i * 128 + w * 16 + l15;
        bf16x8 bw[4];
        #pragma unroll
        for (int ks = 0; ks < 4; ++ks)
            bw[ks] = *(const bf16x8*)(w_inp + (size_t)nrow * 128 + ks * 32 + kg * 8);
        const float bias = inp_b[nrow];
        #pragma unroll
        for (int mt = 0; mt < 8; ++mt) {
            fx4 acc = {bias, bias, bias, bias};
            #pragma unroll
            for (int ks = 0; ks < 4; ++ks) {
                bf16x8 ax = *(const bf16x8*)(xs + (mt * 16 + l15) * 136 + ks * 32 + kg * 8);
                acc = MFMA16(ax, bw[ks], acc);
            }
            if (i == 0) {
                #pragma unroll
                for (int r = 0; r < 4; ++r)
                    qbuf[obase + (mt * 16 + kg * 4 + r) * 16 + l15] = f2bf(acc[r]);
            } else if (i == 1) {
                #pragma unroll
                for (int r = 0; r < 4; ++r)
                    kbuf[obase + (mt * 16 + kg * 4 + r) * 16 + l15] = f2bf(acc[r]);
            } else {
                ushort4 pk;
                pk.x = f2bf(acc[0]); pk.y = f2bf(acc[1]);
                pk.z = f2bf(acc[2]); pk.w = f2bf(acc[3]);
                *(ushort4*)(vbuf + obase + l15 * 128 + mt * 16 + kg * 4) = pk;
            }
        }
    }
}

// --------------------------------------------------------------------------
// K2: attention. Block = (b,h) -> 8192 blocks, 256 thr (4 waves, 2 m-tiles ea).
// k staged [t][18], v staged [d][132] (bank-conflict-free). o overwrites q.
// --------------------------------------------------------------------------
extern "C" __global__ void __launch_bounds__(256, 4)
k_attn(unsigned short* __restrict__ qbuf,
       const unsigned short* __restrict__ kbuf,
       const unsigned short* __restrict__ vbuf,
       const float* __restrict__ mask) {
    __shared__ __align__(16) unsigned short kls[128 * 18];
    __shared__ __align__(16) unsigned short vls[16 * 132];
    __shared__ __align__(16) unsigned short ps[4 * 16 * 40];
    const int tid = threadIdx.x, wv = tid >> 6, lid = tid & 63;
    const int l15 = lid & 15, kg = lid >> 4;
    const int bid = blockIdx.x, b = bid >> 3;
    const size_t base = (size_t)bid * 2048;

    { int row = tid >> 1, half = tid & 1;
      *(float4*)(kls + row * 18 + half * 8) =
          *(const float4*)(kbuf + base + row * 16 + half * 8); }
    { int d = tid >> 4, s = tid & 15;
      *(float4*)(vls + d * 132 + s * 8) =
          *(const float4*)(vbuf + base + d * 128 + s * 8); }
    float mreg[8];
    #pragma unroll
    for (int nt = 0; nt < 8; ++nt) mreg[nt] = mask[b * 128 + nt * 16 + l15];
    __syncthreads();

    unsigned short* psw = ps + wv * 640;
    #pragma unroll 1
    for (int j = 0; j < 2; ++j) {
        const int qrow = (wv * 2 + j) * 16;
        bf16x8 aq = {};
        if (kg < 2) aq = *(const bf16x8*)(qbuf + base + (qrow + l15) * 16 + kg * 8);
        fx4 sc[8];
        #pragma unroll
        for (int nt = 0; nt < 8; ++nt) {
            bf16x8 bk = {};
            if (kg < 2) bk = *(const bf16x8*)(kls + (nt * 16 + l15) * 18 + kg * 8);
            fx4 z = {0.f, 0.f, 0.f, 0.f};
            sc[nt] = MFMA16(aq, bk, z);
        }
        float mx[4], sm[4];
        #pragma unroll
        for (int r = 0; r < 4; ++r) mx[r] = -3.0e38f;
        #pragma unroll
        for (int nt = 0; nt < 8; ++nt)
            #pragma unroll
            for (int r = 0; r < 4; ++r) {
                float v = sc[nt][r] * 0.25f + mreg[nt];
                sc[nt][r] = v;
                mx[r] = fmaxf(mx[r], v);
            }
        #pragma unroll
        for (int s = 1; s < 16; s <<= 1)
            #pragma unroll
            for (int r = 0; r < 4; ++r) mx[r] = fmaxf(mx[r], __shfl_xor(mx[r], s, 64));
        #pragma unroll
        for (int r = 0; r < 4; ++r) sm[r] = 0.f;
        #pragma unroll
        for (int nt = 0; nt < 8; ++nt)
            #pragma unroll
            for (int r = 0; r < 4; ++r) {
                float e = __expf(sc[nt][r] - mx[r]);
                sc[nt][r] = e;
                sm[r] += e;
            }
        #pragma unroll
        for (int s = 1; s < 16; s <<= 1)
            #pragma unroll
            for (int r = 0; r < 4; ++r) sm[r] += __shfl_xor(sm[r], s, 64);
        float inv[4];
        #pragma unroll
        for (int r = 0; r < 4; ++r) inv[r] = 1.f / sm[r];

        fx4 oacc = {0.f, 0.f, 0.f, 0.f};
        #pragma unroll
        for (int c = 0; c < 4; ++c) {
            #pragma unroll
            for (int f = 0; f < 2; ++f) {
                int nt = c * 2 + f;
                #pragma unroll
                for (int r = 0; r < 4; ++r)
                    psw[(kg * 4 + r) * 40 + f * 16 + l15] = f2bf(sc[nt][r] * inv[r]);
            }
            asm volatile("s_waitcnt lgkmcnt(0)" ::: "memory");  // own-wave RAW
            bf16x8 ap = *(const bf16x8*)(psw + l15 * 40 + kg * 8);
            bf16x8 bv = *(const bf16x8*)(vls + l15 * 132 + c * 32 + kg * 8);
            oacc = MFMA16(ap, bv, oacc);
        }
        #pragma unroll
        for (int r = 0; r < 4; ++r)
            qbuf[base + (qrow + kg * 4 + r) * 16 + l15] = f2bf(oacc[r]);
    }
}

// --------------------------------------------------------------------------
// K3: out-proj + bias + residual + LN1, xbuf in-place. Block = b, 512 thr.
// --------------------------------------------------------------------------
extern "C" __global__ void __launch_bounds__(512, 4)
k_oproj(const unsigned short* __restrict__ obuf,
        const unsigned short* __restrict__ w_out,
        const float* __restrict__ out_b,
        const float* __restrict__ ln1g, const float* __restrict__ ln1b,
        unsigned short* __restrict__ xbuf, int l) {
    __shared__ float part_s[1024], part_q[1024], mean_s[128], rstd_s[128];
    const int tid = threadIdx.x, w = tid >> 6, lid = tid & 63;
    const int l15 = lid & 15, kg = lid >> 4, b = blockIdx.x;
    const int col = w * 16 + l15;

    bf16x8 bw[4];
    #pragma unroll
    for (int ks = 0; ks < 4; ++ks)
        bw[ks] = *(const bf16x8*)(w_out + (size_t)(l * 128 + col) * 128 + ks * 32 + kg * 8);
    fx4 acc[8];
    #pragma unroll
    for (int mt = 0; mt < 8; ++mt) {
        fx4 a = {0.f, 0.f, 0.f, 0.f};
        #pragma unroll
        for (int s = 0; s < 4; ++s) {
            bf16x8 af = *(const bf16x8*)(obuf + ((size_t)b * 8 + s * 2 + (kg >> 1)) * 2048
                                         + (mt * 16 + l15) * 16 + (kg & 1) * 8);
            a = MFMA16(af, bw[s], a);
        }
        acc[mt] = a;
    }
    float ob = out_b[l * 128 + col];
    #pragma unroll
    for (int mt = 0; mt < 8; ++mt)
        #pragma unroll
        for (int r = 0; r < 4; ++r)
            acc[mt][r] += ob + bf2f(xbuf[(size_t)b * 16384 + (mt * 16 + kg * 4 + r) * 128 + col]);
    #pragma unroll
    for (int mt = 0; mt < 8; ++mt) {
        fx4 s = acc[mt], q;
        #pragma unroll
        for (int r = 0; r < 4; ++r) q[r] = s[r] * s[r];
        #pragma unroll
        for (int st = 1; st < 16; st <<= 1)
            #pragma unroll
            for (int r = 0; r < 4; ++r) {
                s[r] += __shfl_xor(s[r], st, 64);
                q[r] += __shfl_xor(q[r], st, 64);
            }
        if (l15 == 0) {
            *(fx4*)(part_s + w * 128 + mt * 16 + kg * 4) = s;
            *(fx4*)(part_q + w * 128 + mt * 16 + kg * 4) = q;
        }
    }
    __syncthreads();
    if (tid < 128) {
        float ms = 0.f, mq = 0.f;
        #pragma unroll
        for (int g = 0; g < 8; ++g) { ms += part_s[g * 128 + tid]; mq += part_q[g * 128 + tid]; }
        float mean = ms * 0.0078125f;
        float var  = mq * 0.0078125f - mean * mean;
        mean_s[tid] = mean;
        rstd_s[tid] = rsqrtf(var + 1e-5f);
    }
    __syncthreads();
    float g = ln1g[l * 128 + col], bb = ln1b[l * 128 + col];
    #pragma unroll
    for (int mt = 0; mt < 8; ++mt)
        #pragma unroll
        for (int r = 0; r < 4; ++r) {
            int row = mt * 16 + kg * 4 + r;
            float v = (acc[mt][r] - mean_s[row]) * rstd_s[row] * g + bb;
            xbuf[(size_t)b * 16384 + row * 128 + col] = f2bf(v);
        }
}

// --------------------------------------------------------------------------
// K4: FF1+relu+FF2 + residual + LN2. Block = b, 512 thr, LDS 78 KiB -> 2/CU.
// l=0: write xbuf (bf16, in-place); l=1: write fp32 d_out.
// --------------------------------------------------------------------------
extern "C" __global__ void __launch_bounds__(512, 4)
k_ffn(const unsigned short* __restrict__ xin,
      const unsigned short* __restrict__ w_ff1,
      const unsigned short* __restrict__ w_ff2,
      const float* __restrict__ ff1b, const float* __restrict__ ff2b,
      const float* __restrict__ ln2g, const float* __restrict__ ln2b,
      unsigned short* __restrict__ xout, float* __restrict__ out, int l) {
    __shared__ __align__(16) unsigned short xs[128 * 136];
    __shared__ __align__(16) unsigned short hs[128 * 136];
    __shared__ float part_s[1024], part_q[1024], mean_s[128], rstd_s[128];
    const int tid = threadIdx.x, w = tid >> 6, lid = tid & 63;
    const int l15 = lid & 15, kg = lid >> 4, b = blockIdx.x;

    const unsigned short* xb = xin + (size_t)b * 16384;
    #pragma unroll
    for (int i = 0; i < 4; ++i) {
        int e = i * 4096 + tid * 8;
        int row = e >> 7, col = e & 127;
        *(float4*)(xs + row * 136 + col) = *(const float4*)(xb + e);
    }
    __syncthreads();

    fx4 yacc[8];
    #pragma unroll
    for (int mt = 0; mt < 8; ++mt) { fx4 z = {0.f,0.f,0.f,0.f}; yacc[mt] = z; }

    #pragma unroll 1
    for (int c = 0; c < 4; ++c) {
        {   // FF1 chunk + bias + relu -> hs
            const int nrow = l * 512 + c * 128 + w * 16 + l15;
            bf16x8 b1[4];
            #pragma unroll
            for (int ks = 0; ks < 4; ++ks)
                b1[ks] = *(const bf16x8*)(w_ff1 + (size_t)nrow * 128 + ks * 32 + kg * 8);
            float f1 = ff1b[nrow];
            #pragma unroll
            for (int mt = 0; mt < 8; ++mt) {
                fx4 a = {f1, f1, f1, f1};
                #pragma unroll
                for (int ks = 0; ks < 4; ++ks) {
                    bf16x8 ax = *(const bf16x8*)(xs + (mt * 16 + l15) * 136 + ks * 32 + kg * 8);
                    a = MFMA16(ax, b1[ks], a);
                }
                #pragma unroll
                for (int r = 0; r < 4; ++r)
                    hs[(mt * 16 + kg * 4 + r) * 136 + w * 16 + l15] = f2bf(fmaxf(a[r], 0.f));
            }
        }
        __syncthreads();
        {   // FF2 partial accumulate
            bf16x8 b2[4];
            #pragma unroll
            for (int ks = 0; ks < 4; ++ks)
                b2[ks] = *(const bf16x8*)(w_ff2 + (size_t)(l * 128 + w * 16 + l15) * 512
                                          + c * 128 + ks * 32 + kg * 8);
            #pragma unroll
            for (int mt = 0; mt < 8; ++mt) {
                #pragma unroll
                for (int ks = 0; ks < 4; ++ks) {
                    bf16x8 ah = *(const bf16x8*)(hs + (mt * 16 + l15) * 136 + ks * 32 + kg * 8);
                    yacc[mt] = MFMA16(ah, b2[ks], yacc[mt]);
                }
            }
        }
        __syncthreads();
    }

    const int col = w * 16 + l15;
    float fb = ff2b[l * 128 + col];
    #pragma unroll
    for (int mt = 0; mt < 8; ++mt)
        #pragma unroll
        for (int r = 0; r < 4; ++r)
            yacc[mt][r] += fb + bf2f(xs[(mt * 16 + kg * 4 + r) * 136 + col]);
    #pragma unroll
    for (int mt = 0; mt < 8; ++mt) {
        fx4 s = yacc[mt], q;
        #pragma unroll
        for (int r = 0; r < 4; ++r) q[r] = s[r] * s[r];
        #pragma unroll
        for (int st = 1; st < 16; st <<= 1)
            #pragma unroll
            for (int r = 0; r < 4; ++r) {
                s[r] += __shfl_xor(s[r], st, 64);
                q[r] += __shfl_xor(q[r], st, 64);
            }
        if (l15 == 0) {
            *(fx4*)(part_s + w * 128 + mt * 16 + kg * 4) = s;
            *(fx4*)(part_q + w * 128 + mt * 16 + kg * 4) = q;
        }
    }
    __syncthreads();
    if (tid < 128) {
        float ms = 0.f, mq = 0.f;
        #pragma unroll
        for (int g = 0; g < 8; ++g) { ms += part_s[g * 128 + tid]; mq += part_q[g * 128 + tid]; }
        float mean = ms * 0.0078125f;
        float var  = mq * 0.0078125f - mean * mean;
        mean_s[tid] = mean;
        rstd_s[tid] = rsqrtf(var + 1e-5f);
    }
    __syncthreads();
    float g = ln2g[l * 128 + col], bb = ln2b[l * 128 + col];
    if (l == 1) {
        float* ob = out + (size_t)b * 16384;
        #pragma unroll
        for (int mt = 0; mt < 8; ++mt)
            #pragma unroll
            for (int r = 0; r < 4; ++r) {
                int row = mt * 16 + kg * 4 + r;
                ob[row * 128 + col] = (yacc[mt][r] - mean_s[row]) * rstd_s[row] * g + bb;
            }
    } else {
        #pragma unroll
        for (int mt = 0; mt < 8; ++mt)
            #pragma unroll
            for (int r = 0; r < 4; ++r) {
                int row = mt * 16 + kg * 4 + r;
                float v = (yacc[mt][r] - mean_s[row]) * rstd_s[row] * g + bb;
                xout[(size_t)b * 16384 + row * 128 + col] = f2bf(v);
            }
    }
}

// --------------------------------------------------------------------------
extern "C" void kernel_launch(void* const* d_in, const int* in_sizes, int n_in,
                              void* d_out, int out_size, void* d_ws, size_t ws_size,
                              hipStream_t stream) {
    const float* x    = (const float*)d_in[0];
    const float* mask = (const float*)d_in[1];
    const float* w_in = (const float*)d_in[2];
    const float* b_in = (const float*)d_in[3];
    const float* w_o  = (const float*)d_in[4];
    const float* b_o  = (const float*)d_in[5];
    const float* g1   = (const float*)d_in[6];
    const float* bb1  = (const float*)d_in[7];
    const float* w1   = (const float*)d_in[8];
    const float* b1   = (const float*)d_in[9];
    const float* w2   = (const float*)d_in[10];
    const float* b2   = (const float*)d_in[11];
    const float* g2   = (const float*)d_in[12];
    const float* bb2  = (const float*)d_in[13];

    unsigned short* wsw  = (unsigned short*)d_ws;       // bf16 weights
    unsigned short* qbuf = wsw + 393216;                // q / o, per-head layout
    unsigned short* xbuf = qbuf + 16777216;             // running x (bf16)
    unsigned short* kbuf = (unsigned short*)d_out;      // k scratch (dead by final write)
    unsigned short* vbuf = kbuf + 16777216;             // v scratch (transposed)

    prep<<<16768, 256, 0, stream>>>(w_in, w_o, w1, w2, x, wsw, xbuf);
    for (int l = 0; l < 2; ++l) {
        k_qkv<<<1024, 512, 0, stream>>>(xbuf, wsw, b_in, qbuf, kbuf, vbuf, l);
        k_attn<<<8192, 256, 0, stream>>>(qbuf, kbuf, vbuf, mask);
        k_oproj<<<1024, 512, 0, stream>>>(qbuf, wsw + 98304, b_o, g1, bb1, xbuf, l);
        k_ffn<<<1024, 512, 0, stream>>>(xbuf, wsw + 131072, wsw + 262144,
                                        b1, b2, g2, bb2, xbuf, (float*)d_out, l);
    }
}